// Round 1
// baseline (14588.388 us; speedup 1.0000x reference)
//
#include <hip/hip_runtime.h>
#include <math.h>

// Problem constants (match reference)
#define NN   50000
#define FF   128
#define RBFD 20
#define EE   800000
#define C3F  384
#define TE   32      // rows (edges/nodes) per block tile
#define KC   16      // k-chunk staged in LDS
#define HP   36      // padded stride for [k][row] LDS tiles (36*4=144B, 16B-aligned)

__device__ __forceinline__ float softplus_m_log2(float x) {
  // stable softplus(x) - log(2)
  return fmaxf(x, 0.0f) + log1pf(expf(-fabsf(x))) - 0.6931471805599453f;
}

// -------------------- per-node phi GEMM: phi_all[n][0:128]=phi_s, [128:256]=phi_r
__global__ __launch_bounds__(256, 2)
void phi_kernel(const float* __restrict__ s, const float* __restrict__ phi_W,
                const float* __restrict__ phi_b, float* __restrict__ phi_all) {
  __shared__ float s_t[FF * HP];     // [k][row]
  __shared__ float w_ch[KC * 256];   // k-chunk, segs {0,2} packed as 256 cols
  const int tid = threadIdx.x;
  const int r0 = blockIdx.x * TE;

  for (int i = tid; i < TE * (FF / 4); i += 256) {
    int row = i >> 5, k4 = i & 31;
    int rg = r0 + row;
    float4 sv = make_float4(0.f, 0.f, 0.f, 0.f);
    if (rg < NN) sv = *(const float4*)(s + (size_t)rg * FF + k4 * 4);
    s_t[(k4 * 4 + 0) * HP + row] = sv.x;
    s_t[(k4 * 4 + 1) * HP + row] = sv.y;
    s_t[(k4 * 4 + 2) * HP + row] = sv.z;
    s_t[(k4 * 4 + 3) * HP + row] = sv.w;
  }
  const int tc = tid & 31, tr = tid >> 5;
  float acc[2][4][4];
#pragma unroll
  for (int g = 0; g < 2; ++g)
#pragma unroll
    for (int a = 0; a < 4; ++a)
#pragma unroll
      for (int b = 0; b < 4; ++b) acc[g][a][b] = 0.f;

  for (int kc = 0; kc < FF / KC; ++kc) {
    __syncthreads();
    for (int i = tid; i < KC * 64; i += 256) {
      int k = i >> 6, j4 = i & 63;
      int j = j4 * 4;
      int col = (j < 128) ? j : (j + 128);  // seg0 -> cols 0..127, seg2 -> 256..383
      *(float4*)&w_ch[k * 256 + j] =
          *(const float4*)(phi_W + (size_t)(kc * KC + k) * C3F + col);
    }
    __syncthreads();
#pragma unroll
    for (int k = 0; k < KC; ++k) {
      float4 s4 = *(const float4*)&s_t[(kc * KC + k) * HP + tr * 4];
      float sr[4] = {s4.x, s4.y, s4.z, s4.w};
#pragma unroll
      for (int g = 0; g < 2; ++g) {
        float4 w4 = *(const float4*)&w_ch[k * 256 + g * 128 + tc * 4];
        float wr[4] = {w4.x, w4.y, w4.z, w4.w};
#pragma unroll
        for (int er = 0; er < 4; ++er)
#pragma unroll
          for (int fc = 0; fc < 4; ++fc) acc[g][er][fc] += sr[er] * wr[fc];
      }
    }
  }
  const int f0 = tc * 4;
  float4 b0 = *(const float4*)(phi_b + f0);
  float4 b2 = *(const float4*)(phi_b + 256 + f0);
  float bb[2][4] = {{b0.x, b0.y, b0.z, b0.w}, {b2.x, b2.y, b2.z, b2.w}};
#pragma unroll
  for (int er = 0; er < 4; ++er) {
    int rg = r0 + tr * 4 + er;
    if (rg >= NN) continue;
#pragma unroll
    for (int g = 0; g < 2; ++g) {
      float4 o;
      o.x = acc[g][er][0] + bb[g][0];
      o.y = acc[g][er][1] + bb[g][1];
      o.z = acc[g][er][2] + bb[g][2];
      o.w = acc[g][er][3] + bb[g][3];
      *(float4*)(phi_all + (size_t)rg * 256 + g * 128 + f0) = o;
    }
  }
}

// -------------------- fused edge kernel: filter-net + message + scatter-add
template <bool USE_WS>
__global__ __launch_bounds__(256, 2)
void edge_kernel(const float* __restrict__ sfeat, const float* __restrict__ v,
                 const float* __restrict__ e_ij, const float* __restrict__ r_hat,
                 const float* __restrict__ phi_W, const float* __restrict__ phi_b,
                 const float* __restrict__ f1_W, const float* __restrict__ f1_b,
                 const float* __restrict__ f2_W, const float* __restrict__ f2_b,
                 const int* __restrict__ edge_index,
                 const float* __restrict__ phi_all,
                 float* __restrict__ out_s, float* __restrict__ out_v) {
  __shared__ float h_t[FF * HP];       // [k][e] shifted-softplus filter hidden
  __shared__ float w_ch[KC * C3F];     // weight k-chunk
  __shared__ float e_t[TE * RBFD];     // e_ij tile [e][k]
  __shared__ float f1_lds[RBFD * FF];
  __shared__ int src_lds[TE], dst_lds[TE];
  __shared__ float rh_lds[TE * 3];
  __shared__ float s_t[USE_WS ? 4 : FF * HP];  // gathered s[dst] (inline path only)

  const int tid = threadIdx.x;
  const int e0 = blockIdx.x * TE;  // EE % TE == 0, no guard needed

  if (tid < TE) {
    src_lds[tid] = edge_index[e0 + tid];
    dst_lds[tid] = edge_index[EE + e0 + tid];
  }
  if (tid < TE * 3) rh_lds[tid] = r_hat[(size_t)e0 * 3 + tid];
  for (int i = tid; i < TE * RBFD; i += 256) e_t[i] = e_ij[(size_t)e0 * RBFD + i];
  for (int i = tid; i < RBFD * FF; i += 256) f1_lds[i] = f1_W[i];
  __syncthreads();

  // h = softplus(e_ij @ f1_W + f1_b) - log2, stored transposed [k=f][e]
  for (int i = tid; i < TE * FF; i += 256) {
    int e = i >> 7, f = i & 127;
    float x = f1_b[f];
#pragma unroll
    for (int k = 0; k < RBFD; ++k) x += e_t[e * RBFD + k] * f1_lds[k * FF + f];
    h_t[f * HP + e] = softplus_m_log2(x);
  }
  if constexpr (!USE_WS) {
    for (int i = tid; i < TE * (FF / 4); i += 256) {
      int e = i >> 5, k4 = i & 31;
      int d = dst_lds[e];
      float4 sv = *(const float4*)(sfeat + (size_t)d * FF + k4 * 4);
      s_t[(k4 * 4 + 0) * HP + e] = sv.x;
      s_t[(k4 * 4 + 1) * HP + e] = sv.y;
      s_t[(k4 * 4 + 2) * HP + e] = sv.z;
      s_t[(k4 * 4 + 3) * HP + e] = sv.w;
    }
  }

  const int tc = tid & 31, tr = tid >> 5;
  float facc[3][4][4];
  float pacc[2][4][4];
#pragma unroll
  for (int g = 0; g < 3; ++g)
#pragma unroll
    for (int a = 0; a < 4; ++a)
#pragma unroll
      for (int b = 0; b < 4; ++b) facc[g][a][b] = 0.f;
#pragma unroll
  for (int g = 0; g < 2; ++g)
#pragma unroll
    for (int a = 0; a < 4; ++a)
#pragma unroll
      for (int b = 0; b < 4; ++b) pacc[g][a][b] = 0.f;

  // filt = h @ f2_W  (32e x 384 tile, K=128 in chunks of 16)
  for (int kc = 0; kc < FF / KC; ++kc) {
    __syncthreads();
    for (int i = tid; i < KC * C3F / 4; i += 256)
      *(float4*)&w_ch[i * 4] =
          *(const float4*)(f2_W + (size_t)kc * KC * C3F + i * 4);
    __syncthreads();
#pragma unroll
    for (int k = 0; k < KC; ++k) {
      float4 h4 = *(const float4*)&h_t[(kc * KC + k) * HP + tr * 4];
      float hr[4] = {h4.x, h4.y, h4.z, h4.w};
#pragma unroll
      for (int g = 0; g < 3; ++g) {
        float4 w4 = *(const float4*)&w_ch[k * C3F + g * 128 + tc * 4];
        float wr[4] = {w4.x, w4.y, w4.z, w4.w};
#pragma unroll
        for (int er = 0; er < 4; ++er)
#pragma unroll
          for (int fc = 0; fc < 4; ++fc) facc[g][er][fc] += hr[er] * wr[fc];
      }
    }
  }

  if constexpr (!USE_WS) {
    // inline phi = s[dst] @ phi_W (segs 0 and 2 only)
    for (int kc = 0; kc < FF / KC; ++kc) {
      __syncthreads();
      for (int i = tid; i < KC * 64; i += 256) {
        int k = i >> 6, j4 = i & 63;
        int j = j4 * 4;
        int col = (j < 128) ? j : (j + 128);
        *(float4*)&w_ch[k * C3F + j] =
            *(const float4*)(phi_W + (size_t)(kc * KC + k) * C3F + col);
      }
      __syncthreads();
#pragma unroll
      for (int k = 0; k < KC; ++k) {
        float4 s4 = *(const float4*)&s_t[(kc * KC + k) * HP + tr * 4];
        float sr[4] = {s4.x, s4.y, s4.z, s4.w};
#pragma unroll
        for (int g = 0; g < 2; ++g) {
          float4 w4 = *(const float4*)&w_ch[k * C3F + g * 128 + tc * 4];
          float wr[4] = {w4.x, w4.y, w4.z, w4.w};
#pragma unroll
          for (int er = 0; er < 4; ++er)
#pragma unroll
            for (int fc = 0; fc < 4; ++fc) pacc[g][er][fc] += sr[er] * wr[fc];
        }
      }
    }
  }

  // epilogue: messages + atomics
  const int f0 = tc * 4;
  float4 bs4 = *(const float4*)(f2_b + f0);
  float4 bv4 = *(const float4*)(f2_b + FF + f0);
  float4 br4 = *(const float4*)(f2_b + 2 * FF + f0);
  float bs[4] = {bs4.x, bs4.y, bs4.z, bs4.w};
  float bv[4] = {bv4.x, bv4.y, bv4.z, bv4.w};
  float br[4] = {br4.x, br4.y, br4.z, br4.w};
  float pb0[4], pb2[4];
  if constexpr (!USE_WS) {
    float4 p0 = *(const float4*)(phi_b + f0);
    float4 p2 = *(const float4*)(phi_b + 256 + f0);
    pb0[0] = p0.x; pb0[1] = p0.y; pb0[2] = p0.z; pb0[3] = p0.w;
    pb2[0] = p2.x; pb2[1] = p2.y; pb2[2] = p2.z; pb2[3] = p2.w;
  }

#pragma unroll
  for (int er = 0; er < 4; ++er) {
    const int e = tr * 4 + er;
    const int sg = src_lds[e];
    const int dg = dst_lds[e];
    const float r0c = rh_lds[e * 3 + 0];
    const float r1c = rh_lds[e * 3 + 1];
    const float r2c = rh_lds[e * 3 + 2];

    float ps[4], pr[4];
    if constexpr (USE_WS) {
      float4 p0 = *(const float4*)(phi_all + (size_t)dg * 256 + f0);
      float4 p1 = *(const float4*)(phi_all + (size_t)dg * 256 + 128 + f0);
      ps[0] = p0.x; ps[1] = p0.y; ps[2] = p0.z; ps[3] = p0.w;
      pr[0] = p1.x; pr[1] = p1.y; pr[2] = p1.z; pr[3] = p1.w;
    } else {
#pragma unroll
      for (int fc = 0; fc < 4; ++fc) {
        ps[fc] = pacc[0][er][fc] + pb0[fc];
        pr[fc] = pacc[1][er][fc] + pb2[fc];
      }
    }

    float pv[12];
    const float* vp = v + ((size_t)dg * FF + f0) * 3;
    float4 v0 = *(const float4*)(vp);
    float4 v1 = *(const float4*)(vp + 4);
    float4 v2 = *(const float4*)(vp + 8);
    pv[0] = v0.x; pv[1] = v0.y; pv[2] = v0.z; pv[3] = v0.w;
    pv[4] = v1.x; pv[5] = v1.y; pv[6] = v1.z; pv[7] = v1.w;
    pv[8] = v2.x; pv[9] = v2.y; pv[10] = v2.z; pv[11] = v2.w;

    float* os = out_s + (size_t)sg * FF + f0;
    float* ov = out_v + ((size_t)sg * FF + f0) * 3;
#pragma unroll
    for (int fc = 0; fc < 4; ++fc) {
      float Ws = facc[0][er][fc] + bs[fc];
      float Wv = facc[1][er][fc] + bv[fc];
      float Wr = facc[2][er][fc] + br[fc];
      atomicAdd(os + fc, Ws * ps[fc]);
      float wrp = Wr * pr[fc];
      atomicAdd(ov + fc * 3 + 0, Wv * pv[fc * 3 + 0] + wrp * r0c);
      atomicAdd(ov + fc * 3 + 1, Wv * pv[fc * 3 + 1] + wrp * r1c);
      atomicAdd(ov + fc * 3 + 2, Wv * pv[fc * 3 + 2] + wrp * r2c);
    }
  }
}

extern "C" void kernel_launch(void* const* d_in, const int* in_sizes, int n_in,
                              void* d_out, int out_size, void* d_ws, size_t ws_size,
                              hipStream_t stream) {
  const float* s      = (const float*)d_in[0];
  const float* v      = (const float*)d_in[1];
  const float* e_ij   = (const float*)d_in[2];
  const float* r_hat  = (const float*)d_in[3];
  const float* phi_W  = (const float*)d_in[4];
  const float* phi_b  = (const float*)d_in[5];
  const float* f1_W   = (const float*)d_in[6];
  const float* f1_b   = (const float*)d_in[7];
  const float* f2_W   = (const float*)d_in[8];
  const float* f2_b   = (const float*)d_in[9];
  const int* edge_index = (const int*)d_in[10];

  float* out = (float*)d_out;
  float* out_s = out;                       // (N, F)
  float* out_v = out + (size_t)NN * FF;     // (N, F, 3)

  hipMemsetAsync(d_out, 0, (size_t)out_size * sizeof(float), stream);

  const size_t phi_bytes = (size_t)NN * 256 * sizeof(float);
  const bool use_ws = ws_size >= phi_bytes;

  if (use_ws) {
    float* phi_all = (float*)d_ws;
    phi_kernel<<<(NN + TE - 1) / TE, 256, 0, stream>>>(s, phi_W, phi_b, phi_all);
    edge_kernel<true><<<EE / TE, 256, 0, stream>>>(
        s, v, e_ij, r_hat, phi_W, phi_b, f1_W, f1_b, f2_W, f2_b, edge_index,
        phi_all, out_s, out_v);
  } else {
    edge_kernel<false><<<EE / TE, 256, 0, stream>>>(
        s, v, e_ij, r_hat, phi_W, phi_b, f1_W, f1_b, f2_W, f2_b, edge_index,
        nullptr, out_s, out_v);
  }
}

// Round 2
// 3731.356 us; speedup vs baseline: 3.9097x; 3.9097x over previous
//
#include <hip/hip_runtime.h>
#include <math.h>

// Problem constants (match reference)
#define NN   50000
#define FF   128
#define RBFD 20
#define EE   800000
#define C3F  384
#define TE   32      // edge-parallel fallback tile
#define TN   16      // edges per chunk in node kernel
#define KC   16      // k-chunk staged in LDS
#define HP   36      // padded stride for [k][row] LDS tiles (fallback kernels)
#define HPN  18      // padded stride for node-kernel h tile [k][e], e<16

__device__ __forceinline__ float softplus_m_log2(float x) {
  // stable softplus(x) - log(2)
  return fmaxf(x, 0.0f) + log1pf(expf(-fabsf(x))) - 0.6931471805599453f;
}

// ==================== CSR build ====================
__global__ void hist_kernel(const int* __restrict__ edge_index, int* __restrict__ cursor) {
  int e = blockIdx.x * 256 + threadIdx.x;
  if (e < EE) atomicAdd(&cursor[edge_index[e]], 1);
}

// single-block exclusive scan of cursor[0..NN) -> row_start[0..NN]; also cursor = exclusive
__global__ void scan_kernel(int* __restrict__ cursor, int* __restrict__ row_start) {
  __shared__ int buf[1024];
  __shared__ int carry;
  const int tid = threadIdx.x;
  if (tid == 0) carry = 0;
  __syncthreads();
  for (int base = 0; base < NN; base += 1024) {
    int i = base + tid;
    int x = (i < NN) ? cursor[i] : 0;
    buf[tid] = x;
    __syncthreads();
#pragma unroll
    for (int off = 1; off < 1024; off <<= 1) {
      int val = (tid >= off) ? buf[tid - off] : 0;
      __syncthreads();
      buf[tid] += val;
      __syncthreads();
    }
    int incl = buf[tid];
    int excl = carry + incl - x;
    if (i < NN) { row_start[i] = excl; cursor[i] = excl; }
    __syncthreads();
    if (tid == 1023) carry += incl;
    __syncthreads();
  }
  if (tid == 0) row_start[NN] = carry;  // == EE
}

__global__ void fill_kernel(const int* __restrict__ edge_index, int* __restrict__ cursor,
                            int* __restrict__ perm) {
  int e = blockIdx.x * 256 + threadIdx.x;
  if (e < EE) {
    int s = edge_index[e];
    int pos = atomicAdd(&cursor[s], 1);
    perm[pos] = e;
  }
}

// ==================== per-node phi GEMM: phi_all[n][0:128]=phi_s+b, [128:256]=phi_r+b
__global__ __launch_bounds__(256, 2)
void phi_kernel(const float* __restrict__ s, const float* __restrict__ phi_W,
                const float* __restrict__ phi_b, float* __restrict__ phi_all) {
  __shared__ float s_t[FF * HP];     // [k][row]
  __shared__ float w_ch[KC * 256];   // k-chunk, segs {0,2} packed as 256 cols
  const int tid = threadIdx.x;
  const int r0 = blockIdx.x * TE;

  for (int i = tid; i < TE * (FF / 4); i += 256) {
    int row = i >> 5, k4 = i & 31;
    int rg = r0 + row;
    float4 sv = make_float4(0.f, 0.f, 0.f, 0.f);
    if (rg < NN) sv = *(const float4*)(s + (size_t)rg * FF + k4 * 4);
    s_t[(k4 * 4 + 0) * HP + row] = sv.x;
    s_t[(k4 * 4 + 1) * HP + row] = sv.y;
    s_t[(k4 * 4 + 2) * HP + row] = sv.z;
    s_t[(k4 * 4 + 3) * HP + row] = sv.w;
  }
  const int tc = tid & 31, tr = tid >> 5;
  float acc[2][4][4];
#pragma unroll
  for (int g = 0; g < 2; ++g)
#pragma unroll
    for (int a = 0; a < 4; ++a)
#pragma unroll
      for (int b = 0; b < 4; ++b) acc[g][a][b] = 0.f;

  for (int kc = 0; kc < FF / KC; ++kc) {
    __syncthreads();
    for (int i = tid; i < KC * 64; i += 256) {
      int k = i >> 6, j4 = i & 63;
      int j = j4 * 4;
      int col = (j < 128) ? j : (j + 128);
      *(float4*)&w_ch[k * 256 + j] =
          *(const float4*)(phi_W + (size_t)(kc * KC + k) * C3F + col);
    }
    __syncthreads();
#pragma unroll
    for (int k = 0; k < KC; ++k) {
      float4 s4 = *(const float4*)&s_t[(kc * KC + k) * HP + tr * 4];
      float sr[4] = {s4.x, s4.y, s4.z, s4.w};
#pragma unroll
      for (int g = 0; g < 2; ++g) {
        float4 w4 = *(const float4*)&w_ch[k * 256 + g * 128 + tc * 4];
        float wr[4] = {w4.x, w4.y, w4.z, w4.w};
#pragma unroll
        for (int er = 0; er < 4; ++er)
#pragma unroll
          for (int fc = 0; fc < 4; ++fc) acc[g][er][fc] += sr[er] * wr[fc];
      }
    }
  }
  const int f0 = tc * 4;
  float4 b0 = *(const float4*)(phi_b + f0);
  float4 b2 = *(const float4*)(phi_b + 256 + f0);
  float bb[2][4] = {{b0.x, b0.y, b0.z, b0.w}, {b2.x, b2.y, b2.z, b2.w}};
#pragma unroll
  for (int er = 0; er < 4; ++er) {
    int rg = r0 + tr * 4 + er;
    if (rg >= NN) continue;
#pragma unroll
    for (int g = 0; g < 2; ++g) {
      float4 o;
      o.x = acc[g][er][0] + bb[g][0];
      o.y = acc[g][er][1] + bb[g][1];
      o.z = acc[g][er][2] + bb[g][2];
      o.w = acc[g][er][3] + bb[g][3];
      *(float4*)(phi_all + (size_t)rg * 256 + g * 128 + f0) = o;
    }
  }
}

// ==================== node-centric main kernel: NO fp32 atomics ====================
// one block per node; chunks of TN=16 edges; direct stores of delta_s/delta_v
__global__ __launch_bounds__(256, 3)
void node_kernel(const float* __restrict__ v, const float* __restrict__ e_ij,
                 const float* __restrict__ r_hat,
                 const float* __restrict__ f1_W, const float* __restrict__ f1_b,
                 const float* __restrict__ f2_W, const float* __restrict__ f2_b,
                 const int* __restrict__ edge_index,
                 const int* __restrict__ row_start, const int* __restrict__ perm,
                 const float* __restrict__ phi_all,
                 float* __restrict__ out_s, float* __restrict__ out_v) {
  __shared__ float h_t[FF * HPN];      // [k=f][e], e<16, pad stride 18
  __shared__ float w_ch[KC * C3F];     // 24 KB; reused as reduction buffer at end
  __shared__ float e_t[TN * RBFD];
  __shared__ float f1_lds[RBFD * FF];
  __shared__ float f1b_lds[FF];
  __shared__ int el[TN], dl[TN];

  const int n = blockIdx.x;
  const int tid = threadIdx.x;
  const int tc = tid & 31, tr = tid >> 5;
  const int rs = row_start[n];
  const int deg = row_start[n + 1] - rs;

  for (int i = tid; i < RBFD * FF; i += 256) f1_lds[i] = f1_W[i];
  if (tid < FF) f1b_lds[tid] = f1_b[tid];

  const int f0 = tc * 4;
  float4 bs4 = *(const float4*)(f2_b + f0);
  float4 bv4 = *(const float4*)(f2_b + FF + f0);
  float4 br4 = *(const float4*)(f2_b + 2 * FF + f0);
  float bs[4] = {bs4.x, bs4.y, bs4.z, bs4.w};
  float bv[4] = {bv4.x, bv4.y, bv4.z, bv4.w};
  float br[4] = {br4.x, br4.y, br4.z, br4.w};

  float ds_acc[4] = {0.f, 0.f, 0.f, 0.f};
  float dv_acc[4][3];
#pragma unroll
  for (int a = 0; a < 4; ++a)
#pragma unroll
    for (int c = 0; c < 3; ++c) dv_acc[a][c] = 0.f;

  for (int c0 = 0; c0 < deg; c0 += TN) {
    __syncthreads();  // protect el/dl/e_t/h_t from previous chunk's readers
    if (tid < TN) {
      int idx = c0 + tid;
      int eid = (idx < deg) ? perm[rs + idx] : -1;
      el[tid] = eid;
      dl[tid] = (eid >= 0) ? edge_index[EE + eid] : 0;
    }
    __syncthreads();
    for (int i = tid; i < TN * RBFD; i += 256) {
      int e = i / RBFD, k = i - e * RBFD;
      int eid = el[e];
      e_t[i] = (eid >= 0) ? e_ij[(size_t)eid * RBFD + k] : 0.f;
    }
    __syncthreads();
    // h = softplus(e_ij @ f1_W + f1_b) - log2, transposed [f][e]
    for (int i = tid; i < TN * FF; i += 256) {
      int e = i >> 7, f = i & 127;
      float x = f1b_lds[f];
#pragma unroll
      for (int k = 0; k < RBFD; ++k) x += e_t[e * RBFD + k] * f1_lds[k * FF + f];
      h_t[f * HPN + e] = (el[e] >= 0) ? softplus_m_log2(x) : 0.f;
    }

    float facc[3][2][4];
#pragma unroll
    for (int g = 0; g < 3; ++g)
#pragma unroll
      for (int a = 0; a < 2; ++a)
#pragma unroll
        for (int b = 0; b < 4; ++b) facc[g][a][b] = 0.f;

    // filt = h @ f2_W  (16e x 384, K=128 in chunks of 16)
    for (int kcs = 0; kcs < FF / KC; ++kcs) {
      __syncthreads();
      for (int i = tid; i < KC * C3F / 4; i += 256)
        *(float4*)&w_ch[i * 4] =
            *(const float4*)(f2_W + (size_t)kcs * KC * C3F + i * 4);
      __syncthreads();
#pragma unroll
      for (int k = 0; k < KC; ++k) {
        float2 h2 = *(const float2*)&h_t[(kcs * KC + k) * HPN + tr * 2];
        float hr[2] = {h2.x, h2.y};
#pragma unroll
        for (int g = 0; g < 3; ++g) {
          float4 w4 = *(const float4*)&w_ch[k * C3F + g * 128 + tc * 4];
          float wr[4] = {w4.x, w4.y, w4.z, w4.w};
#pragma unroll
          for (int er = 0; er < 2; ++er)
#pragma unroll
            for (int fc = 0; fc < 4; ++fc) facc[g][er][fc] += hr[er] * wr[fc];
        }
      }
    }

    // epilogue: per-edge message, accumulate into per-thread node accumulators
#pragma unroll
    for (int er = 0; er < 2; ++er) {
      const int e = tr * 2 + er;
      const int eid = el[e];
      if (eid < 0) continue;
      const int dg = dl[e];
      float4 p0 = *(const float4*)(phi_all + (size_t)dg * 256 + f0);
      float4 p1 = *(const float4*)(phi_all + (size_t)dg * 256 + 128 + f0);
      float ps[4] = {p0.x, p0.y, p0.z, p0.w};
      float pr[4] = {p1.x, p1.y, p1.z, p1.w};
      const float* vp = v + ((size_t)dg * FF + f0) * 3;
      float4 v0 = *(const float4*)(vp);
      float4 v1 = *(const float4*)(vp + 4);
      float4 v2 = *(const float4*)(vp + 8);
      float pv[12] = {v0.x, v0.y, v0.z, v0.w, v1.x, v1.y, v1.z, v1.w,
                      v2.x, v2.y, v2.z, v2.w};
      float rh0 = r_hat[(size_t)eid * 3 + 0];
      float rh1 = r_hat[(size_t)eid * 3 + 1];
      float rh2 = r_hat[(size_t)eid * 3 + 2];
#pragma unroll
      for (int fc = 0; fc < 4; ++fc) {
        float Ws = facc[0][er][fc] + bs[fc];
        float Wv = facc[1][er][fc] + bv[fc];
        float Wr = facc[2][er][fc] + br[fc];
        ds_acc[fc] += Ws * ps[fc];
        float wrp = Wr * pr[fc];
        dv_acc[fc][0] += Wv * pv[fc * 3 + 0] + wrp * rh0;
        dv_acc[fc][1] += Wv * pv[fc * 3 + 1] + wrp * rh1;
        dv_acc[fc][2] += Wv * pv[fc * 3 + 2] + wrp * rh2;
      }
    }
  }

  // cross-wave reduction over tr (8 partials per feature), then direct store
  __syncthreads();
  float* red_v = w_ch;              // [8][384] = 12 KB
  float* red_s = w_ch + 8 * C3F;    // [8][128] = 4 KB
#pragma unroll
  for (int fc = 0; fc < 4; ++fc) {
    red_s[tr * FF + f0 + fc] = ds_acc[fc];
#pragma unroll
    for (int c = 0; c < 3; ++c)
      red_v[tr * C3F + (f0 + fc) * 3 + c] = dv_acc[fc][c];
  }
  __syncthreads();
  if (tid < FF) {
    float x = 0.f;
#pragma unroll
    for (int p = 0; p < 8; ++p) x += red_s[p * FF + tid];
    out_s[(size_t)n * FF + tid] = x;
  }
  for (int i = tid; i < C3F; i += 256) {
    float x = 0.f;
#pragma unroll
    for (int p = 0; p < 8; ++p) x += red_v[p * C3F + i];
    out_v[(size_t)n * C3F + i] = x;
  }
}

// ==================== fallback: edge-parallel with atomics (small ws) ====================
template <bool USE_WS>
__global__ __launch_bounds__(256, 2)
void edge_kernel(const float* __restrict__ sfeat, const float* __restrict__ v,
                 const float* __restrict__ e_ij, const float* __restrict__ r_hat,
                 const float* __restrict__ phi_W, const float* __restrict__ phi_b,
                 const float* __restrict__ f1_W, const float* __restrict__ f1_b,
                 const float* __restrict__ f2_W, const float* __restrict__ f2_b,
                 const int* __restrict__ edge_index,
                 const float* __restrict__ phi_all,
                 float* __restrict__ out_s, float* __restrict__ out_v) {
  __shared__ float h_t[FF * HP];
  __shared__ float w_ch[KC * C3F];
  __shared__ float e_t[TE * RBFD];
  __shared__ float f1_lds[RBFD * FF];
  __shared__ int src_lds[TE], dst_lds[TE];
  __shared__ float rh_lds[TE * 3];
  __shared__ float s_t[USE_WS ? 4 : FF * HP];

  const int tid = threadIdx.x;
  const int e0 = blockIdx.x * TE;

  if (tid < TE) {
    src_lds[tid] = edge_index[e0 + tid];
    dst_lds[tid] = edge_index[EE + e0 + tid];
  }
  if (tid < TE * 3) rh_lds[tid] = r_hat[(size_t)e0 * 3 + tid];
  for (int i = tid; i < TE * RBFD; i += 256) e_t[i] = e_ij[(size_t)e0 * RBFD + i];
  for (int i = tid; i < RBFD * FF; i += 256) f1_lds[i] = f1_W[i];
  __syncthreads();

  for (int i = tid; i < TE * FF; i += 256) {
    int e = i >> 7, f = i & 127;
    float x = f1_b[f];
#pragma unroll
    for (int k = 0; k < RBFD; ++k) x += e_t[e * RBFD + k] * f1_lds[k * FF + f];
    h_t[f * HP + e] = softplus_m_log2(x);
  }
  if constexpr (!USE_WS) {
    for (int i = tid; i < TE * (FF / 4); i += 256) {
      int e = i >> 5, k4 = i & 31;
      int d = dst_lds[e];
      float4 sv = *(const float4*)(sfeat + (size_t)d * FF + k4 * 4);
      s_t[(k4 * 4 + 0) * HP + e] = sv.x;
      s_t[(k4 * 4 + 1) * HP + e] = sv.y;
      s_t[(k4 * 4 + 2) * HP + e] = sv.z;
      s_t[(k4 * 4 + 3) * HP + e] = sv.w;
    }
  }

  const int tc = tid & 31, tr = tid >> 5;
  float facc[3][4][4];
  float pacc[2][4][4];
#pragma unroll
  for (int g = 0; g < 3; ++g)
#pragma unroll
    for (int a = 0; a < 4; ++a)
#pragma unroll
      for (int b = 0; b < 4; ++b) facc[g][a][b] = 0.f;
#pragma unroll
  for (int g = 0; g < 2; ++g)
#pragma unroll
    for (int a = 0; a < 4; ++a)
#pragma unroll
      for (int b = 0; b < 4; ++b) pacc[g][a][b] = 0.f;

  for (int kc = 0; kc < FF / KC; ++kc) {
    __syncthreads();
    for (int i = tid; i < KC * C3F / 4; i += 256)
      *(float4*)&w_ch[i * 4] =
          *(const float4*)(f2_W + (size_t)kc * KC * C3F + i * 4);
    __syncthreads();
#pragma unroll
    for (int k = 0; k < KC; ++k) {
      float4 h4 = *(const float4*)&h_t[(kc * KC + k) * HP + tr * 4];
      float hr[4] = {h4.x, h4.y, h4.z, h4.w};
#pragma unroll
      for (int g = 0; g < 3; ++g) {
        float4 w4 = *(const float4*)&w_ch[k * C3F + g * 128 + tc * 4];
        float wr[4] = {w4.x, w4.y, w4.z, w4.w};
#pragma unroll
        for (int er = 0; er < 4; ++er)
#pragma unroll
          for (int fc = 0; fc < 4; ++fc) facc[g][er][fc] += hr[er] * wr[fc];
      }
    }
  }

  if constexpr (!USE_WS) {
    for (int kc = 0; kc < FF / KC; ++kc) {
      __syncthreads();
      for (int i = tid; i < KC * 64; i += 256) {
        int k = i >> 6, j4 = i & 63;
        int j = j4 * 4;
        int col = (j < 128) ? j : (j + 128);
        *(float4*)&w_ch[k * C3F + j] =
            *(const float4*)(phi_W + (size_t)(kc * KC + k) * C3F + col);
      }
      __syncthreads();
#pragma unroll
      for (int k = 0; k < KC; ++k) {
        float4 s4 = *(const float4*)&s_t[(kc * KC + k) * HP + tr * 4];
        float sr[4] = {s4.x, s4.y, s4.z, s4.w};
#pragma unroll
        for (int g = 0; g < 2; ++g) {
          float4 w4 = *(const float4*)&w_ch[k * C3F + g * 128 + tc * 4];
          float wr[4] = {w4.x, w4.y, w4.z, w4.w};
#pragma unroll
          for (int er = 0; er < 4; ++er)
#pragma unroll
            for (int fc = 0; fc < 4; ++fc) pacc[g][er][fc] += sr[er] * wr[fc];
        }
      }
    }
  }

  const int f0 = tc * 4;
  float4 bs4 = *(const float4*)(f2_b + f0);
  float4 bv4 = *(const float4*)(f2_b + FF + f0);
  float4 br4 = *(const float4*)(f2_b + 2 * FF + f0);
  float bs[4] = {bs4.x, bs4.y, bs4.z, bs4.w};
  float bv[4] = {bv4.x, bv4.y, bv4.z, bv4.w};
  float br[4] = {br4.x, br4.y, br4.z, br4.w};
  float pb0[4], pb2[4];
  if constexpr (!USE_WS) {
    float4 p0 = *(const float4*)(phi_b + f0);
    float4 p2 = *(const float4*)(phi_b + 256 + f0);
    pb0[0] = p0.x; pb0[1] = p0.y; pb0[2] = p0.z; pb0[3] = p0.w;
    pb2[0] = p2.x; pb2[1] = p2.y; pb2[2] = p2.z; pb2[3] = p2.w;
  }

#pragma unroll
  for (int er = 0; er < 4; ++er) {
    const int e = tr * 4 + er;
    const int sg = src_lds[e];
    const int dg = dst_lds[e];
    const float r0c = rh_lds[e * 3 + 0];
    const float r1c = rh_lds[e * 3 + 1];
    const float r2c = rh_lds[e * 3 + 2];

    float ps[4], pr[4];
    if constexpr (USE_WS) {
      float4 p0 = *(const float4*)(phi_all + (size_t)dg * 256 + f0);
      float4 p1 = *(const float4*)(phi_all + (size_t)dg * 256 + 128 + f0);
      ps[0] = p0.x; ps[1] = p0.y; ps[2] = p0.z; ps[3] = p0.w;
      pr[0] = p1.x; pr[1] = p1.y; pr[2] = p1.z; pr[3] = p1.w;
    } else {
#pragma unroll
      for (int fc = 0; fc < 4; ++fc) {
        ps[fc] = pacc[0][er][fc] + pb0[fc];
        pr[fc] = pacc[1][er][fc] + pb2[fc];
      }
    }

    float pv[12];
    const float* vp = v + ((size_t)dg * FF + f0) * 3;
    float4 v0 = *(const float4*)(vp);
    float4 v1 = *(const float4*)(vp + 4);
    float4 v2 = *(const float4*)(vp + 8);
    pv[0] = v0.x; pv[1] = v0.y; pv[2] = v0.z; pv[3] = v0.w;
    pv[4] = v1.x; pv[5] = v1.y; pv[6] = v1.z; pv[7] = v1.w;
    pv[8] = v2.x; pv[9] = v2.y; pv[10] = v2.z; pv[11] = v2.w;

    float* os = out_s + (size_t)sg * FF + f0;
    float* ov = out_v + ((size_t)sg * FF + f0) * 3;
#pragma unroll
    for (int fc = 0; fc < 4; ++fc) {
      float Ws = facc[0][er][fc] + bs[fc];
      float Wv = facc[1][er][fc] + bv[fc];
      float Wr = facc[2][er][fc] + br[fc];
      atomicAdd(os + fc, Ws * ps[fc]);
      float wrp = Wr * pr[fc];
      atomicAdd(ov + fc * 3 + 0, Wv * pv[fc * 3 + 0] + wrp * r0c);
      atomicAdd(ov + fc * 3 + 1, Wv * pv[fc * 3 + 1] + wrp * r1c);
      atomicAdd(ov + fc * 3 + 2, Wv * pv[fc * 3 + 2] + wrp * r2c);
    }
  }
}

extern "C" void kernel_launch(void* const* d_in, const int* in_sizes, int n_in,
                              void* d_out, int out_size, void* d_ws, size_t ws_size,
                              hipStream_t stream) {
  const float* s      = (const float*)d_in[0];
  const float* v      = (const float*)d_in[1];
  const float* e_ij   = (const float*)d_in[2];
  const float* r_hat  = (const float*)d_in[3];
  const float* phi_W  = (const float*)d_in[4];
  const float* phi_b  = (const float*)d_in[5];
  const float* f1_W   = (const float*)d_in[6];
  const float* f1_b   = (const float*)d_in[7];
  const float* f2_W   = (const float*)d_in[8];
  const float* f2_b   = (const float*)d_in[9];
  const int* edge_index = (const int*)d_in[10];

  float* out = (float*)d_out;
  float* out_s = out;                       // (N, F)
  float* out_v = out + (size_t)NN * FF;     // (N, F, 3)

  // ws layout (full path):
  //   row_start: int[NN+1] (padded to 50008)
  //   cursor:    int[NN]
  //   perm:      int[EE]
  //   phi_all:   float[NN*256]
  int* row_start = (int*)d_ws;
  int* cursor    = row_start + 50008;
  int* perm      = cursor + NN;
  float* phi_all_full = (float*)(perm + EE);
  const size_t full_bytes = (size_t)(50008 + NN + EE) * 4 + (size_t)NN * 256 * 4;
  const size_t phi_bytes  = (size_t)NN * 256 * sizeof(float);

  if (ws_size >= full_bytes) {
    hipMemsetAsync(cursor, 0, (size_t)NN * sizeof(int), stream);
    hist_kernel<<<(EE + 255) / 256, 256, 0, stream>>>(edge_index, cursor);
    scan_kernel<<<1, 1024, 0, stream>>>(cursor, row_start);
    fill_kernel<<<(EE + 255) / 256, 256, 0, stream>>>(edge_index, cursor, perm);
    phi_kernel<<<(NN + TE - 1) / TE, 256, 0, stream>>>(s, phi_W, phi_b, phi_all_full);
    node_kernel<<<NN, 256, 0, stream>>>(v, e_ij, r_hat, f1_W, f1_b, f2_W, f2_b,
                                        edge_index, row_start, perm, phi_all_full,
                                        out_s, out_v);
  } else if (ws_size >= phi_bytes) {
    hipMemsetAsync(d_out, 0, (size_t)out_size * sizeof(float), stream);
    float* phi_all = (float*)d_ws;
    phi_kernel<<<(NN + TE - 1) / TE, 256, 0, stream>>>(s, phi_W, phi_b, phi_all);
    edge_kernel<true><<<EE / TE, 256, 0, stream>>>(
        s, v, e_ij, r_hat, phi_W, phi_b, f1_W, f1_b, f2_W, f2_b, edge_index,
        phi_all, out_s, out_v);
  } else {
    hipMemsetAsync(d_out, 0, (size_t)out_size * sizeof(float), stream);
    edge_kernel<false><<<EE / TE, 256, 0, stream>>>(
        s, v, e_ij, r_hat, phi_W, phi_b, f1_W, f1_b, f2_W, f2_b, edge_index,
        nullptr, out_s, out_v);
  }
}

// Round 3
// 2072.318 us; speedup vs baseline: 7.0396x; 1.8006x over previous
//
#include <hip/hip_runtime.h>
#include <math.h>

// Problem constants (match reference)
#define NN   50000
#define FF   128
#define RBFD 20
#define EE   800000
#define C3F  384
#define TE   32      // edge-parallel fallback tile
#define TN   16      // edges per chunk in node kernel (MFMA M=16)
#define KC   16      // k-chunk staged in LDS (fallback kernels)
#define HP   36      // padded stride for fallback LDS tiles

typedef __attribute__((ext_vector_type(8))) short bhalf8;   // 8 bf16 (4 VGPRs)
typedef __attribute__((ext_vector_type(4))) float floatx4;  // MFMA acc

__device__ __forceinline__ float softplus_m_log2(float x) {
  return fmaxf(x, 0.0f) + log1pf(expf(-fabsf(x))) - 0.6931471805599453f;
}

__device__ __forceinline__ short f2bf(float x) {
  unsigned u = __float_as_uint(x);
  u += 0x7fffu + ((u >> 16) & 1u);   // round-to-nearest-even
  return (short)(u >> 16);
}

// ==================== CSR build ====================
__global__ void hist_kernel(const int* __restrict__ edge_index, int* __restrict__ cursor) {
  int e = blockIdx.x * 256 + threadIdx.x;
  if (e < EE) atomicAdd(&cursor[edge_index[e]], 1);
}

__global__ void scan_kernel(int* __restrict__ cursor, int* __restrict__ row_start) {
  __shared__ int buf[1024];
  __shared__ int carry;
  const int tid = threadIdx.x;
  if (tid == 0) carry = 0;
  __syncthreads();
  for (int base = 0; base < NN; base += 1024) {
    int i = base + tid;
    int x = (i < NN) ? cursor[i] : 0;
    buf[tid] = x;
    __syncthreads();
#pragma unroll
    for (int off = 1; off < 1024; off <<= 1) {
      int val = (tid >= off) ? buf[tid - off] : 0;
      __syncthreads();
      buf[tid] += val;
      __syncthreads();
    }
    int incl = buf[tid];
    int excl = carry + incl - x;
    if (i < NN) { row_start[i] = excl; cursor[i] = excl; }
    __syncthreads();
    if (tid == 1023) carry += incl;
    __syncthreads();
  }
  if (tid == 0) row_start[NN] = carry;
}

__global__ void fill_kernel(const int* __restrict__ edge_index, int* __restrict__ cursor,
                            int* __restrict__ perm) {
  int e = blockIdx.x * 256 + threadIdx.x;
  if (e < EE) {
    int s = edge_index[e];
    int pos = atomicAdd(&cursor[s], 1);
    perm[pos] = e;
  }
}

// ==================== weight conversion: f2t[n][k]=bf16(f2_W[k][n]); f1t[f][40] padded
__global__ void conv_kernel(const float* __restrict__ f1_W, const float* __restrict__ f2_W,
                            short* __restrict__ f1t, short* __restrict__ f2t) {
  int i = blockIdx.x * 256 + threadIdx.x;
  if (i < C3F * FF) {
    int n = i >> 7, k = i & 127;
    f2t[i] = f2bf(f2_W[(size_t)k * C3F + n]);
  }
  if (i < FF * 40) {
    int f = i / 40, k = i - f * 40;
    f1t[i] = (k < RBFD) ? f2bf(f1_W[(size_t)k * FF + f]) : (short)0;
  }
}

// ==================== per-node phi GEMM: phi_all[n][0:128]=phi_s+b, [128:256]=phi_r+b
__global__ __launch_bounds__(256, 2)
void phi_kernel(const float* __restrict__ s, const float* __restrict__ phi_W,
                const float* __restrict__ phi_b, float* __restrict__ phi_all) {
  __shared__ float s_t[FF * HP];
  __shared__ float w_ch[KC * 256];
  const int tid = threadIdx.x;
  const int r0 = blockIdx.x * TE;

  for (int i = tid; i < TE * (FF / 4); i += 256) {
    int row = i >> 5, k4 = i & 31;
    int rg = r0 + row;
    float4 sv = make_float4(0.f, 0.f, 0.f, 0.f);
    if (rg < NN) sv = *(const float4*)(s + (size_t)rg * FF + k4 * 4);
    s_t[(k4 * 4 + 0) * HP + row] = sv.x;
    s_t[(k4 * 4 + 1) * HP + row] = sv.y;
    s_t[(k4 * 4 + 2) * HP + row] = sv.z;
    s_t[(k4 * 4 + 3) * HP + row] = sv.w;
  }
  const int tc = tid & 31, tr = tid >> 5;
  float acc[2][4][4];
#pragma unroll
  for (int g = 0; g < 2; ++g)
#pragma unroll
    for (int a = 0; a < 4; ++a)
#pragma unroll
      for (int b = 0; b < 4; ++b) acc[g][a][b] = 0.f;

  for (int kc = 0; kc < FF / KC; ++kc) {
    __syncthreads();
    for (int i = tid; i < KC * 64; i += 256) {
      int k = i >> 6, j4 = i & 63;
      int j = j4 * 4;
      int col = (j < 128) ? j : (j + 128);
      *(float4*)&w_ch[k * 256 + j] =
          *(const float4*)(phi_W + (size_t)(kc * KC + k) * C3F + col);
    }
    __syncthreads();
#pragma unroll
    for (int k = 0; k < KC; ++k) {
      float4 s4 = *(const float4*)&s_t[(kc * KC + k) * HP + tr * 4];
      float sr[4] = {s4.x, s4.y, s4.z, s4.w};
#pragma unroll
      for (int g = 0; g < 2; ++g) {
        float4 w4 = *(const float4*)&w_ch[k * 256 + g * 128 + tc * 4];
        float wr[4] = {w4.x, w4.y, w4.z, w4.w};
#pragma unroll
        for (int er = 0; er < 4; ++er)
#pragma unroll
          for (int fc = 0; fc < 4; ++fc) acc[g][er][fc] += sr[er] * wr[fc];
      }
    }
  }
  const int f0 = tc * 4;
  float4 b0 = *(const float4*)(phi_b + f0);
  float4 b2 = *(const float4*)(phi_b + 256 + f0);
  float bb[2][4] = {{b0.x, b0.y, b0.z, b0.w}, {b2.x, b2.y, b2.z, b2.w}};
#pragma unroll
  for (int er = 0; er < 4; ++er) {
    int rg = r0 + tr * 4 + er;
    if (rg >= NN) continue;
#pragma unroll
    for (int g = 0; g < 2; ++g) {
      float4 o;
      o.x = acc[g][er][0] + bb[g][0];
      o.y = acc[g][er][1] + bb[g][1];
      o.z = acc[g][er][2] + bb[g][2];
      o.w = acc[g][er][3] + bb[g][3];
      *(float4*)(phi_all + (size_t)rg * 256 + g * 128 + f0) = o;
    }
  }
}

// ==================== node-centric MFMA kernel ====================
// 4 waves/block; wave w owns features f in [w*32, w*32+32).
// h-GEMM: 16x16x32 bf16, A=e_ij padded to K=32, B=f1t (LDS, hoisted to regs).
// filt-GEMM: K=128 (4 k-steps), B=f2t fragments held in VGPRs across all chunks.
// C-layout epilogue: lane holds col f=lane&15(+16), rows e=quad*4+r.
// Node accumulators per-lane, reduced across quads via shfl_xor; no atomics.
__global__ __launch_bounds__(256, 3)
void node_mfma_kernel(const float* __restrict__ v, const float* __restrict__ e_ij,
                      const float* __restrict__ r_hat,
                      const float* __restrict__ f1_b, const float* __restrict__ f2_b,
                      const int* __restrict__ edge_index,
                      const int* __restrict__ row_start, const int* __restrict__ perm,
                      const float* __restrict__ phi_all,
                      const short* __restrict__ f1t_g, const short* __restrict__ f2t_g,
                      float* __restrict__ out_s, float* __restrict__ out_v) {
  __shared__ short f1t_l[FF * 40];     // [f][k] bf16, k<20 data else 0 (10 KB)
  __shared__ short e_pad[TN * 40];     // [e][k] bf16, K padded to 32 (1.25 KB)
  __shared__ short h_buf[TN * 136];    // [e][f] bf16 (4.25 KB)
  __shared__ float rh_l[TN * 3];
  __shared__ int dl[TN];

  const int n = blockIdx.x;
  const int tid = threadIdx.x;
  const int wid = tid >> 6;
  const int lane = tid & 63;
  const int l = lane & 15;       // col within tile
  const int q = lane >> 4;       // quad
  const int rs = row_start[n];
  const int deg = row_start[n + 1] - rs;

  // stage f1t into LDS (once)
  for (int i = tid; i < FF * 40 / 2; i += 256)
    ((int*)f1t_l)[i] = ((const int*)f1t_g)[i];

  const int f0 = wid * 32 + l;
  const int f1 = f0 + 16;

  // per-lane biases
  const float f1b0 = f1_b[f0], f1b1 = f1_b[f1];
  const float bs0 = f2_b[f0],        bs1 = f2_b[f1];
  const float bv0 = f2_b[FF + f0],   bv1 = f2_b[FF + f1];
  const float br0 = f2_b[2*FF + f0], br1 = f2_b[2*FF + f1];

  // B fragments for filt-GEMM, invariant across chunks: tile j = g*2+hh covers
  // n-cols g*128 + wid*32 + hh*16 + l, k-range = ks*32 + q*8.
  bhalf8 Bfr[6][4];
#pragma unroll
  for (int j = 0; j < 6; ++j) {
    int g = j >> 1, hh = j & 1;
    int nc = g * 128 + wid * 32 + hh * 16 + l;
#pragma unroll
    for (int ks = 0; ks < 4; ++ks)
      Bfr[j][ks] = *(const bhalf8*)(f2t_g + (size_t)nc * FF + ks * 32 + q * 8);
  }

  __syncthreads();
  // hoist f1 B-fragments (invariant): B[k][n=f0/f1] from f1t_l[n][k]
  const bhalf8 b1f0 = *(const bhalf8*)(&f1t_l[f0 * 40 + q * 8]);
  const bhalf8 b1f1 = *(const bhalf8*)(&f1t_l[f1 * 40 + q * 8]);

  float dsA[2] = {0.f, 0.f};
  float dvA[2][3] = {{0.f, 0.f, 0.f}, {0.f, 0.f, 0.f}};

  for (int c0 = 0; c0 < deg; c0 += TN) {
    const int cnt = min(TN, deg - c0);
    __syncthreads();  // protect e_pad/h_buf/dl/rh_l from previous chunk readers

    if (tid < TN) {
      int idx = c0 + tid;
      int eid = (idx < deg) ? perm[rs + idx] : -1;
      dl[tid] = (eid >= 0) ? edge_index[EE + eid] : 0;
      if (eid >= 0) {
        rh_l[tid * 3 + 0] = r_hat[(size_t)eid * 3 + 0];
        rh_l[tid * 3 + 1] = r_hat[(size_t)eid * 3 + 1];
        rh_l[tid * 3 + 2] = r_hat[(size_t)eid * 3 + 2];
      } else {
        rh_l[tid * 3 + 0] = 0.f; rh_l[tid * 3 + 1] = 0.f; rh_l[tid * 3 + 2] = 0.f;
      }
    }
    // e_pad: [e][k] bf16, zeros beyond k=20 / invalid edges
    for (int i = tid; i < TN * 32; i += 256) {
      int e = i >> 5, k = i & 31;
      int idx = c0 + e;
      float val = 0.f;
      if (idx < deg && k < RBFD) {
        int eid = perm[rs + idx];
        val = e_ij[(size_t)eid * RBFD + k];
      }
      e_pad[e * 40 + k] = f2bf(val);
    }
    __syncthreads();

    // ---- h-GEMM: 16 edges x 32 f-cols per wave, K=32 (one MFMA per 16-col tile)
    {
      bhalf8 a = *(const bhalf8*)(&e_pad[l * 40 + q * 8]);
      floatx4 h0 = {0.f, 0.f, 0.f, 0.f}, h1 = {0.f, 0.f, 0.f, 0.f};
      h0 = __builtin_amdgcn_mfma_f32_16x16x32_bf16(a, b1f0, h0, 0, 0, 0);
      h1 = __builtin_amdgcn_mfma_f32_16x16x32_bf16(a, b1f1, h1, 0, 0, 0);
#pragma unroll
      for (int r = 0; r < 4; ++r) {
        int e = q * 4 + r;
        h_buf[e * 136 + f0] = f2bf(softplus_m_log2(h0[r] + f1b0));
        h_buf[e * 136 + f1] = f2bf(softplus_m_log2(h1[r] + f1b1));
      }
    }
    __syncthreads();

    // ---- filt-GEMM: K=128, B in registers
    floatx4 acc[6];
#pragma unroll
    for (int j = 0; j < 6; ++j) acc[j] = (floatx4){0.f, 0.f, 0.f, 0.f};
#pragma unroll
    for (int ks = 0; ks < 4; ++ks) {
      bhalf8 a = *(const bhalf8*)(&h_buf[l * 136 + ks * 32 + q * 8]);
#pragma unroll
      for (int j = 0; j < 6; ++j)
        acc[j] = __builtin_amdgcn_mfma_f32_16x16x32_bf16(a, Bfr[j][ks], acc[j], 0, 0, 0);
    }

    // ---- epilogue: per-lane gathers + node accumulation
#pragma unroll
    for (int r = 0; r < 4; ++r) {
      int e = q * 4 + r;
      if (e < cnt) {
        int dg = dl[e];
        float Ws0 = acc[0][r] + bs0, Ws1 = acc[1][r] + bs1;
        float Wv0 = acc[2][r] + bv0, Wv1 = acc[3][r] + bv1;
        float Wr0 = acc[4][r] + br0, Wr1 = acc[5][r] + br1;
        const float* pp = phi_all + (size_t)dg * 256;
        float ps0 = pp[f0], ps1 = pp[f1];
        float pr0 = pp[FF + f0], pr1 = pp[FF + f1];
        const float* vp0 = v + ((size_t)dg * FF + f0) * 3;
        const float* vp1 = v + ((size_t)dg * FF + f1) * 3;
        float rh0 = rh_l[e * 3 + 0], rh1 = rh_l[e * 3 + 1], rh2 = rh_l[e * 3 + 2];
        dsA[0] += Ws0 * ps0;
        dsA[1] += Ws1 * ps1;
        float w0 = Wr0 * pr0, w1 = Wr1 * pr1;
        dvA[0][0] += Wv0 * vp0[0] + w0 * rh0;
        dvA[0][1] += Wv0 * vp0[1] + w0 * rh1;
        dvA[0][2] += Wv0 * vp0[2] + w0 * rh2;
        dvA[1][0] += Wv1 * vp1[0] + w1 * rh0;
        dvA[1][1] += Wv1 * vp1[1] + w1 * rh1;
        dvA[1][2] += Wv1 * vp1[2] + w1 * rh2;
      }
    }
  }

  // quad reduction (lanes with equal lane&15 hold the same feature)
#pragma unroll
  for (int a = 0; a < 2; ++a) {
    dsA[a] += __shfl_xor(dsA[a], 16);
    dsA[a] += __shfl_xor(dsA[a], 32);
#pragma unroll
    for (int c = 0; c < 3; ++c) {
      dvA[a][c] += __shfl_xor(dvA[a][c], 16);
      dvA[a][c] += __shfl_xor(dvA[a][c], 32);
    }
  }
  if (q == 0) {
    out_s[(size_t)n * FF + f0] = dsA[0];
    out_s[(size_t)n * FF + f1] = dsA[1];
    float* ov0 = out_v + ((size_t)n * FF + f0) * 3;
    float* ov1 = out_v + ((size_t)n * FF + f1) * 3;
    ov0[0] = dvA[0][0]; ov0[1] = dvA[0][1]; ov0[2] = dvA[0][2];
    ov1[0] = dvA[1][0]; ov1[1] = dvA[1][1]; ov1[2] = dvA[1][2];
  }
}

// ==================== fallback: edge-parallel with atomics (small ws) ====================
template <bool USE_WS>
__global__ __launch_bounds__(256, 2)
void edge_kernel(const float* __restrict__ sfeat, const float* __restrict__ v,
                 const float* __restrict__ e_ij, const float* __restrict__ r_hat,
                 const float* __restrict__ phi_W, const float* __restrict__ phi_b,
                 const float* __restrict__ f1_W, const float* __restrict__ f1_b,
                 const float* __restrict__ f2_W, const float* __restrict__ f2_b,
                 const int* __restrict__ edge_index,
                 const float* __restrict__ phi_all,
                 float* __restrict__ out_s, float* __restrict__ out_v) {
  __shared__ float h_t[FF * HP];
  __shared__ float w_ch[KC * C3F];
  __shared__ float e_t[TE * RBFD];
  __shared__ float f1_lds[RBFD * FF];
  __shared__ int src_lds[TE], dst_lds[TE];
  __shared__ float rh_lds[TE * 3];
  __shared__ float s_t[USE_WS ? 4 : FF * HP];

  const int tid = threadIdx.x;
  const int e0 = blockIdx.x * TE;

  if (tid < TE) {
    src_lds[tid] = edge_index[e0 + tid];
    dst_lds[tid] = edge_index[EE + e0 + tid];
  }
  if (tid < TE * 3) rh_lds[tid] = r_hat[(size_t)e0 * 3 + tid];
  for (int i = tid; i < TE * RBFD; i += 256) e_t[i] = e_ij[(size_t)e0 * RBFD + i];
  for (int i = tid; i < RBFD * FF; i += 256) f1_lds[i] = f1_W[i];
  __syncthreads();

  for (int i = tid; i < TE * FF; i += 256) {
    int e = i >> 7, f = i & 127;
    float x = f1_b[f];
#pragma unroll
    for (int k = 0; k < RBFD; ++k) x += e_t[e * RBFD + k] * f1_lds[k * FF + f];
    h_t[f * HP + e] = softplus_m_log2(x);
  }
  if constexpr (!USE_WS) {
    for (int i = tid; i < TE * (FF / 4); i += 256) {
      int e = i >> 5, k4 = i & 31;
      int d = dst_lds[e];
      float4 sv = *(const float4*)(sfeat + (size_t)d * FF + k4 * 4);
      s_t[(k4 * 4 + 0) * HP + e] = sv.x;
      s_t[(k4 * 4 + 1) * HP + e] = sv.y;
      s_t[(k4 * 4 + 2) * HP + e] = sv.z;
      s_t[(k4 * 4 + 3) * HP + e] = sv.w;
    }
  }

  const int tc = tid & 31, tr = tid >> 5;
  float facc[3][4][4];
  float pacc[2][4][4];
#pragma unroll
  for (int g = 0; g < 3; ++g)
#pragma unroll
    for (int a = 0; a < 4; ++a)
#pragma unroll
      for (int b = 0; b < 4; ++b) facc[g][a][b] = 0.f;
#pragma unroll
  for (int g = 0; g < 2; ++g)
#pragma unroll
    for (int a = 0; a < 4; ++a)
#pragma unroll
      for (int b = 0; b < 4; ++b) pacc[g][a][b] = 0.f;

  for (int kc = 0; kc < FF / KC; ++kc) {
    __syncthreads();
    for (int i = tid; i < KC * C3F / 4; i += 256)
      *(float4*)&w_ch[i * 4] =
          *(const float4*)(f2_W + (size_t)kc * KC * C3F + i * 4);
    __syncthreads();
#pragma unroll
    for (int k = 0; k < KC; ++k) {
      float4 h4 = *(const float4*)&h_t[(kc * KC + k) * HP + tr * 4];
      float hr[4] = {h4.x, h4.y, h4.z, h4.w};
#pragma unroll
      for (int g = 0; g < 3; ++g) {
        float4 w4 = *(const float4*)&w_ch[k * C3F + g * 128 + tc * 4];
        float wr[4] = {w4.x, w4.y, w4.z, w4.w};
#pragma unroll
        for (int er = 0; er < 4; ++er)
#pragma unroll
          for (int fc = 0; fc < 4; ++fc) facc[g][er][fc] += hr[er] * wr[fc];
      }
    }
  }

  if constexpr (!USE_WS) {
    for (int kc = 0; kc < FF / KC; ++kc) {
      __syncthreads();
      for (int i = tid; i < KC * 64; i += 256) {
        int k = i >> 6, j4 = i & 63;
        int j = j4 * 4;
        int col = (j < 128) ? j : (j + 128);
        *(float4*)&w_ch[k * C3F + j] =
            *(const float4*)(phi_W + (size_t)(kc * KC + k) * C3F + col);
      }
      __syncthreads();
#pragma unroll
      for (int k = 0; k < KC; ++k) {
        float4 s4 = *(const float4*)&s_t[(kc * KC + k) * HP + tr * 4];
        float sr[4] = {s4.x, s4.y, s4.z, s4.w};
#pragma unroll
        for (int g = 0; g < 2; ++g) {
          float4 w4 = *(const float4*)&w_ch[k * C3F + g * 128 + tc * 4];
          float wr[4] = {w4.x, w4.y, w4.z, w4.w};
#pragma unroll
          for (int er = 0; er < 4; ++er)
#pragma unroll
            for (int fc = 0; fc < 4; ++fc) pacc[g][er][fc] += sr[er] * wr[fc];
        }
      }
    }
  }

  const int f0 = tc * 4;
  float4 bs4 = *(const float4*)(f2_b + f0);
  float4 bv4 = *(const float4*)(f2_b + FF + f0);
  float4 br4 = *(const float4*)(f2_b + 2 * FF + f0);
  float bs[4] = {bs4.x, bs4.y, bs4.z, bs4.w};
  float bv[4] = {bv4.x, bv4.y, bv4.z, bv4.w};
  float br[4] = {br4.x, br4.y, br4.z, br4.w};
  float pb0[4], pb2[4];
  if constexpr (!USE_WS) {
    float4 p0 = *(const float4*)(phi_b + f0);
    float4 p2 = *(const float4*)(phi_b + 256 + f0);
    pb0[0] = p0.x; pb0[1] = p0.y; pb0[2] = p0.z; pb0[3] = p0.w;
    pb2[0] = p2.x; pb2[1] = p2.y; pb2[2] = p2.z; pb2[3] = p2.w;
  }

#pragma unroll
  for (int er = 0; er < 4; ++er) {
    const int e = tr * 4 + er;
    const int sg = src_lds[e];
    const int dg = dst_lds[e];
    const float r0c = rh_lds[e * 3 + 0];
    const float r1c = rh_lds[e * 3 + 1];
    const float r2c = rh_lds[e * 3 + 2];

    float ps[4], pr[4];
    if constexpr (USE_WS) {
      float4 p0 = *(const float4*)(phi_all + (size_t)dg * 256 + f0);
      float4 p1 = *(const float4*)(phi_all + (size_t)dg * 256 + 128 + f0);
      ps[0] = p0.x; ps[1] = p0.y; ps[2] = p0.z; ps[3] = p0.w;
      pr[0] = p1.x; pr[1] = p1.y; pr[2] = p1.z; pr[3] = p1.w;
    } else {
#pragma unroll
      for (int fc = 0; fc < 4; ++fc) {
        ps[fc] = pacc[0][er][fc] + pb0[fc];
        pr[fc] = pacc[1][er][fc] + pb2[fc];
      }
    }

    float pv[12];
    const float* vp = v + ((size_t)dg * FF + f0) * 3;
    float4 v0 = *(const float4*)(vp);
    float4 v1 = *(const float4*)(vp + 4);
    float4 v2 = *(const float4*)(vp + 8);
    pv[0] = v0.x; pv[1] = v0.y; pv[2] = v0.z; pv[3] = v0.w;
    pv[4] = v1.x; pv[5] = v1.y; pv[6] = v1.z; pv[7] = v1.w;
    pv[8] = v2.x; pv[9] = v2.y; pv[10] = v2.z; pv[11] = v2.w;

    float* os = out_s + (size_t)sg * FF + f0;
    float* ov = out_v + ((size_t)sg * FF + f0) * 3;
#pragma unroll
    for (int fc = 0; fc < 4; ++fc) {
      float Ws = facc[0][er][fc] + bs[fc];
      float Wv = facc[1][er][fc] + bv[fc];
      float Wr = facc[2][er][fc] + br[fc];
      atomicAdd(os + fc, Ws * ps[fc]);
      float wrp = Wr * pr[fc];
      atomicAdd(ov + fc * 3 + 0, Wv * pv[fc * 3 + 0] + wrp * r0c);
      atomicAdd(ov + fc * 3 + 1, Wv * pv[fc * 3 + 1] + wrp * r1c);
      atomicAdd(ov + fc * 3 + 2, Wv * pv[fc * 3 + 2] + wrp * r2c);
    }
  }
}

extern "C" void kernel_launch(void* const* d_in, const int* in_sizes, int n_in,
                              void* d_out, int out_size, void* d_ws, size_t ws_size,
                              hipStream_t stream) {
  const float* s      = (const float*)d_in[0];
  const float* v      = (const float*)d_in[1];
  const float* e_ij   = (const float*)d_in[2];
  const float* r_hat  = (const float*)d_in[3];
  const float* phi_W  = (const float*)d_in[4];
  const float* phi_b  = (const float*)d_in[5];
  const float* f1_W   = (const float*)d_in[6];
  const float* f1_b   = (const float*)d_in[7];
  const float* f2_W   = (const float*)d_in[8];
  const float* f2_b   = (const float*)d_in[9];
  const int* edge_index = (const int*)d_in[10];

  float* out = (float*)d_out;
  float* out_s = out;                       // (N, F)
  float* out_v = out + (size_t)NN * FF;     // (N, F, 3)

  // ws layout: row_start[50008] | cursor[NN] | perm[EE] | phi_all[NN*256] f32
  //            | f2t[384*128] bf16 | f1t[128*40] bf16
  int* row_start = (int*)d_ws;
  int* cursor    = row_start + 50008;
  int* perm      = cursor + NN;
  float* phi_all = (float*)(perm + EE);
  short* f2t     = (short*)(phi_all + (size_t)NN * 256);
  short* f1t     = f2t + C3F * FF;
  const size_t full_bytes = (size_t)(50008 + NN + EE) * 4 +
                            (size_t)NN * 256 * 4 + (size_t)(C3F * FF + FF * 40) * 2;
  const size_t phi_bytes = (size_t)NN * 256 * sizeof(float);

  if (ws_size >= full_bytes) {
    hipMemsetAsync(cursor, 0, (size_t)NN * sizeof(int), stream);
    hist_kernel<<<(EE + 255) / 256, 256, 0, stream>>>(edge_index, cursor);
    scan_kernel<<<1, 1024, 0, stream>>>(cursor, row_start);
    fill_kernel<<<(EE + 255) / 256, 256, 0, stream>>>(edge_index, cursor, perm);
    conv_kernel<<<(C3F * FF + 255) / 256, 256, 0, stream>>>(f1_W, f2_W, f1t, f2t);
    phi_kernel<<<(NN + TE - 1) / TE, 256, 0, stream>>>(s, phi_W, phi_b, phi_all);
    node_mfma_kernel<<<NN, 256, 0, stream>>>(v, e_ij, r_hat, f1_b, f2_b,
                                             edge_index, row_start, perm, phi_all,
                                             f1t, f2t, out_s, out_v);
  } else if (ws_size >= phi_bytes) {
    hipMemsetAsync(d_out, 0, (size_t)out_size * sizeof(float), stream);
    float* phi_all2 = (float*)d_ws;
    phi_kernel<<<(NN + TE - 1) / TE, 256, 0, stream>>>(s, phi_W, phi_b, phi_all2);
    edge_kernel<true><<<EE / TE, 256, 0, stream>>>(
        s, v, e_ij, r_hat, phi_W, phi_b, f1_W, f1_b, f2_W, f2_b, edge_index,
        phi_all2, out_s, out_v);
  } else {
    hipMemsetAsync(d_out, 0, (size_t)out_size * sizeof(float), stream);
    edge_kernel<false><<<EE / TE, 256, 0, stream>>>(
        s, v, e_ij, r_hat, phi_W, phi_b, f1_W, f1_b, f2_W, f2_b, edge_index,
        nullptr, out_s, out_v);
  }
}

// Round 4
// 1503.778 us; speedup vs baseline: 9.7012x; 1.3781x over previous
//
#include <hip/hip_runtime.h>
#include <math.h>

// Problem constants (match reference)
#define NN   50000
#define FF   128
#define RBFD 20
#define EE   800000
#define C3F  384
#define TE   32      // phi tile / fallback tile
#define TN   16      // edges per chunk in node kernel (MFMA M=16)
#define KC   16      // k-chunk staged in LDS (fallback kernels)
#define HP   36      // padded stride for fallback LDS tiles

typedef __attribute__((ext_vector_type(8))) short bhalf8;   // 8 bf16 (4 VGPRs)
typedef __attribute__((ext_vector_type(4))) float floatx4;  // MFMA acc

__device__ __forceinline__ float softplus_m_log2(float x) {
  float t = __expf(-fabsf(x));
  return fmaxf(x, 0.0f) + __logf(1.0f + t) - 0.6931471805599453f;
}

__device__ __forceinline__ short f2bf(float x) {
  unsigned u = __float_as_uint(x);
  u += 0x7fffu + ((u >> 16) & 1u);   // round-to-nearest-even
  return (short)(u >> 16);
}
__device__ __forceinline__ float bflo(unsigned u) { return __uint_as_float(u << 16); }
__device__ __forceinline__ float bfhi(unsigned u) { return __uint_as_float(u & 0xffff0000u); }

// packed feature index: pairs (f, f+16) adjacent within each 32-feature group
__device__ __forceinline__ int pkf(int f) {
  return ((f >> 5) << 5) | ((f & 15) << 1) | ((f >> 4) & 1);
}

// ==================== CSR build ====================
__global__ void hist_kernel(const int* __restrict__ edge_index, int* __restrict__ cursor) {
  int e = blockIdx.x * 256 + threadIdx.x;
  if (e < EE) atomicAdd(&cursor[edge_index[e]], 1);
}

// single-block scan, each thread owns 49 consecutive elements
__global__ void scan_kernel(int* __restrict__ cursor, int* __restrict__ row_start) {
  __shared__ int sums[1024];
  const int tid = threadIdx.x;
  const int CH = 49;                 // 49*1024 >= NN
  int base = tid * CH;
  int vals[CH];
  int local = 0;
#pragma unroll
  for (int j = 0; j < CH; ++j) {
    int i = base + j;
    int x = (i < NN) ? cursor[i] : 0;
    vals[j] = x;
    local += x;
  }
  sums[tid] = local;
  __syncthreads();
  for (int off = 1; off < 1024; off <<= 1) {
    int v2 = (tid >= off) ? sums[tid - off] : 0;
    __syncthreads();
    sums[tid] += v2;
    __syncthreads();
  }
  int excl = sums[tid] - local;
#pragma unroll
  for (int j = 0; j < CH; ++j) {
    int i = base + j;
    if (i < NN) { row_start[i] = excl; cursor[i] = excl; }
    excl += vals[j];
  }
  if (tid == 1023) row_start[NN] = excl;
}

__global__ void fill_kernel(const int* __restrict__ edge_index, int* __restrict__ cursor,
                            int* __restrict__ perm) {
  int e = blockIdx.x * 256 + threadIdx.x;
  if (e < EE) {
    int s = edge_index[e];
    int pos = atomicAdd(&cursor[s], 1);
    perm[pos] = e;
  }
}

// ==================== weight conversion: f2t[n][k]=bf16(f2_W[k][n]); f1t[f][40]
__global__ void conv_kernel(const float* __restrict__ f1_W, const float* __restrict__ f2_W,
                            short* __restrict__ f1t, short* __restrict__ f2t) {
  int i = blockIdx.x * 256 + threadIdx.x;
  if (i < C3F * FF) {
    int n = i >> 7, k = i & 127;
    f2t[i] = f2bf(f2_W[(size_t)k * C3F + n]);
  }
  if (i < FF * 40) {
    int f = i / 40, k = i - f * 40;
    f1t[i] = (k < RBFD) ? f2bf(f1_W[(size_t)k * FF + f]) : (short)0;
  }
}

// ==================== v -> packed bf16: v_b16[n][g*96 + l*6 + c*2 + h]
__global__ void vconv_kernel(const float* __restrict__ v, short* __restrict__ v_b16) {
  int i = blockIdx.x * 256 + threadIdx.x;
  if (i < NN * FF * 3) {
    int n = i / 384;
    int rem = i - n * 384;
    int f = rem / 3;
    int c = rem - f * 3;
    int g = f >> 5, l = f & 15, h = (f >> 4) & 1;
    v_b16[(size_t)n * 384 + g * 96 + l * 6 + c * 2 + h] = f2bf(v[i]);
  }
}

// ==================== per-node phi GEMM -> packed bf16 phi_b16[n][256]
// [0:128] = phi_s+b (pkf layout), [128:256] = phi_r+b
__global__ __launch_bounds__(256, 2)
void phi_kernel(const float* __restrict__ s, const float* __restrict__ phi_W,
                const float* __restrict__ phi_b, short* __restrict__ phi_b16) {
  __shared__ float s_t[FF * HP];
  __shared__ __align__(16) float w_ch[KC * 256];   // reused as output staging
  const int tid = threadIdx.x;
  const int r0 = blockIdx.x * TE;

  for (int i = tid; i < TE * (FF / 4); i += 256) {
    int row = i >> 5, k4 = i & 31;
    int rg = r0 + row;
    float4 sv = make_float4(0.f, 0.f, 0.f, 0.f);
    if (rg < NN) sv = *(const float4*)(s + (size_t)rg * FF + k4 * 4);
    s_t[(k4 * 4 + 0) * HP + row] = sv.x;
    s_t[(k4 * 4 + 1) * HP + row] = sv.y;
    s_t[(k4 * 4 + 2) * HP + row] = sv.z;
    s_t[(k4 * 4 + 3) * HP + row] = sv.w;
  }
  const int tc = tid & 31, tr = tid >> 5;
  float acc[2][4][4];
#pragma unroll
  for (int g = 0; g < 2; ++g)
#pragma unroll
    for (int a = 0; a < 4; ++a)
#pragma unroll
      for (int b = 0; b < 4; ++b) acc[g][a][b] = 0.f;

  for (int kc = 0; kc < FF / KC; ++kc) {
    __syncthreads();
    for (int i = tid; i < KC * 64; i += 256) {
      int k = i >> 6, j4 = i & 63;
      int j = j4 * 4;
      int col = (j < 128) ? j : (j + 128);
      *(float4*)&w_ch[k * 256 + j] =
          *(const float4*)(phi_W + (size_t)(kc * KC + k) * C3F + col);
    }
    __syncthreads();
#pragma unroll
    for (int k = 0; k < KC; ++k) {
      float4 s4 = *(const float4*)&s_t[(kc * KC + k) * HP + tr * 4];
      float sr[4] = {s4.x, s4.y, s4.z, s4.w};
#pragma unroll
      for (int g = 0; g < 2; ++g) {
        float4 w4 = *(const float4*)&w_ch[k * 256 + g * 128 + tc * 4];
        float wr[4] = {w4.x, w4.y, w4.z, w4.w};
#pragma unroll
        for (int er = 0; er < 4; ++er)
#pragma unroll
          for (int fc = 0; fc < 4; ++fc) acc[g][er][fc] += sr[er] * wr[fc];
      }
    }
  }
  const int f0 = tc * 4;
  float4 b0 = *(const float4*)(phi_b + f0);
  float4 b2 = *(const float4*)(phi_b + 256 + f0);
  float bb[2][4] = {{b0.x, b0.y, b0.z, b0.w}, {b2.x, b2.y, b2.z, b2.w}};

  __syncthreads();                       // done reading w_ch as weights
  short* ob = (short*)w_ch;              // [32 rows][256] packed bf16
#pragma unroll
  for (int er = 0; er < 4; ++er) {
    int row = tr * 4 + er;
#pragma unroll
    for (int g = 0; g < 2; ++g) {
#pragma unroll
      for (int fc = 0; fc < 4; ++fc) {
        int f = f0 + fc;
        ob[row * 256 + g * 128 + pkf(f)] = f2bf(acc[g][er][fc] + bb[g][fc]);
      }
    }
  }
  __syncthreads();
  // coalesced store: 32 rows x 512B = 1024 int4
  for (int i = tid; i < 1024; i += 256) {
    int row = i >> 5;
    int rg = r0 + row;
    if (rg < NN)
      ((int4*)(phi_b16 + (size_t)rg * 256))[i & 31] = ((const int4*)ob)[i];
  }
}

// ==================== node-centric MFMA kernel (persistent blocks) ====================
template <bool VB16>
__global__ __launch_bounds__(256, 3)
void node_mfma_kernel(const float* __restrict__ vf32, const short* __restrict__ v_b16,
                      const float* __restrict__ e_ij, const float* __restrict__ r_hat,
                      const float* __restrict__ f1_b, const float* __restrict__ f2_b,
                      const int* __restrict__ edge_index,
                      const int* __restrict__ row_start, const int* __restrict__ perm,
                      const short* __restrict__ phi_b16,
                      const short* __restrict__ f1t_g, const short* __restrict__ f2t_g,
                      float* __restrict__ out_s, float* __restrict__ out_v) {
  __shared__ __align__(16) short f1t_l[FF * 40];   // 10 KB
  __shared__ __align__(16) short e_pad[TN * 40];   // 1.25 KB
  __shared__ __align__(16) short h_buf[TN * 136];  // 4.25 KB; reused as f32 out staging
  __shared__ float rh_l[TN * 3];
  __shared__ int el[TN], dl[TN];

  const int tid = threadIdx.x;
  const int wid = tid >> 6;
  const int lane = tid & 63;
  const int l = lane & 15;
  const int q = lane >> 4;

  for (int i = tid; i < FF * 40 / 2; i += 256)
    ((int*)f1t_l)[i] = ((const int*)f1t_g)[i];

  const int f0 = wid * 32 + l;
  const int f1 = f0 + 16;

  const float f1b0 = f1_b[f0], f1b1 = f1_b[f1];
  const float bs0 = f2_b[f0],        bs1 = f2_b[f1];
  const float bv0 = f2_b[FF + f0],   bv1 = f2_b[FF + f1];
  const float br0 = f2_b[2*FF + f0], br1 = f2_b[2*FF + f1];

  // filt-GEMM B fragments, loaded ONCE per block (persistent)
  bhalf8 Bfr[6][4];
#pragma unroll
  for (int j = 0; j < 6; ++j) {
    int g = j >> 1, hh = j & 1;
    int nc = g * 128 + wid * 32 + hh * 16 + l;
#pragma unroll
    for (int ks = 0; ks < 4; ++ks)
      Bfr[j][ks] = *(const bhalf8*)(f2t_g + (size_t)nc * FF + ks * 32 + q * 8);
  }

  __syncthreads();
  const bhalf8 b1f0 = *(const bhalf8*)(&f1t_l[f0 * 40 + q * 8]);
  const bhalf8 b1f1 = *(const bhalf8*)(&f1t_l[f1 * 40 + q * 8]);

  for (int n = blockIdx.x; n < NN; n += gridDim.x) {
    const int rs = row_start[n];
    const int deg = row_start[n + 1] - rs;

    float dsA[2] = {0.f, 0.f};
    float dvA[2][3] = {{0.f, 0.f, 0.f}, {0.f, 0.f, 0.f}};

    for (int c0 = 0; c0 < deg; c0 += TN) {
      const int cnt = min(TN, deg - c0);
      __syncthreads();  // protect LDS from previous chunk/node readers

      if (tid < TN) {
        int idx = c0 + tid;
        int eid = (idx < deg) ? perm[rs + idx] : -1;
        el[tid] = eid;
        dl[tid] = (eid >= 0) ? edge_index[EE + eid] : 0;
        if (eid >= 0) {
          rh_l[tid * 3 + 0] = r_hat[(size_t)eid * 3 + 0];
          rh_l[tid * 3 + 1] = r_hat[(size_t)eid * 3 + 1];
          rh_l[tid * 3 + 2] = r_hat[(size_t)eid * 3 + 2];
        } else {
          rh_l[tid * 3 + 0] = 0.f; rh_l[tid * 3 + 1] = 0.f; rh_l[tid * 3 + 2] = 0.f;
        }
      }
      __syncthreads();
      for (int i = tid; i < TN * 32; i += 256) {
        int e = i >> 5, k = i & 31;
        int eid = el[e];
        float val = (eid >= 0 && k < RBFD) ? e_ij[(size_t)eid * RBFD + k] : 0.f;
        e_pad[e * 40 + k] = f2bf(val);
      }
      __syncthreads();

      // ---- h-GEMM: 16 edges x 32 f-cols per wave, K=32
      {
        bhalf8 a = *(const bhalf8*)(&e_pad[l * 40 + q * 8]);
        floatx4 h0 = {0.f, 0.f, 0.f, 0.f}, h1 = {0.f, 0.f, 0.f, 0.f};
        h0 = __builtin_amdgcn_mfma_f32_16x16x32_bf16(a, b1f0, h0, 0, 0, 0);
        h1 = __builtin_amdgcn_mfma_f32_16x16x32_bf16(a, b1f1, h1, 0, 0, 0);
#pragma unroll
        for (int r = 0; r < 4; ++r) {
          int e = q * 4 + r;
          h_buf[e * 136 + f0] = f2bf(softplus_m_log2(h0[r] + f1b0));
          h_buf[e * 136 + f1] = f2bf(softplus_m_log2(h1[r] + f1b1));
        }
      }
      __syncthreads();

      // ---- filt-GEMM: K=128, B resident in registers
      floatx4 acc[6];
#pragma unroll
      for (int j = 0; j < 6; ++j) acc[j] = (floatx4){0.f, 0.f, 0.f, 0.f};
#pragma unroll
      for (int ks = 0; ks < 4; ++ks) {
        bhalf8 a = *(const bhalf8*)(&h_buf[l * 136 + ks * 32 + q * 8]);
#pragma unroll
        for (int j = 0; j < 6; ++j)
          acc[j] = __builtin_amdgcn_mfma_f32_16x16x32_bf16(a, Bfr[j][ks], acc[j], 0, 0, 0);
      }

      // ---- epilogue: branchless masked gathers + node accumulation
#pragma unroll
      for (int r = 0; r < 4; ++r) {
        int e = q * 4 + r;
        int dg = dl[e];
        float valid = (e < cnt) ? 1.0f : 0.0f;
        float Ws0 = (acc[0][r] + bs0) * valid, Ws1 = (acc[1][r] + bs1) * valid;
        float Wv0 = (acc[2][r] + bv0) * valid, Wv1 = (acc[3][r] + bv1) * valid;
        float Wr0 = (acc[4][r] + br0) * valid, Wr1 = (acc[5][r] + br1) * valid;

        const short* pb = phi_b16 + (size_t)dg * 256 + wid * 32 + l * 2;
        unsigned psu = *(const unsigned*)pb;
        unsigned pru = *(const unsigned*)(pb + 128);
        float ps0 = bflo(psu), ps1 = bfhi(psu);
        float pr0 = bflo(pru), pr1 = bfhi(pru);

        float v00, v01, v02, v10, v11, v12;
        if constexpr (VB16) {
          const short* vb = v_b16 + (size_t)dg * 384 + wid * 96 + l * 6;
          unsigned u0 = ((const unsigned*)vb)[0];
          unsigned u1 = ((const unsigned*)vb)[1];
          unsigned u2 = ((const unsigned*)vb)[2];
          v00 = bflo(u0); v10 = bfhi(u0);
          v01 = bflo(u1); v11 = bfhi(u1);
          v02 = bflo(u2); v12 = bfhi(u2);
        } else {
          const float* vp0 = vf32 + ((size_t)dg * FF + f0) * 3;
          const float* vp1 = vf32 + ((size_t)dg * FF + f1) * 3;
          v00 = vp0[0]; v01 = vp0[1]; v02 = vp0[2];
          v10 = vp1[0]; v11 = vp1[1]; v12 = vp1[2];
        }
        float rh0 = rh_l[e * 3 + 0], rh1 = rh_l[e * 3 + 1], rh2 = rh_l[e * 3 + 2];
        dsA[0] += Ws0 * ps0;
        dsA[1] += Ws1 * ps1;
        float w0 = Wr0 * pr0, w1 = Wr1 * pr1;
        dvA[0][0] += Wv0 * v00 + w0 * rh0;
        dvA[0][1] += Wv0 * v01 + w0 * rh1;
        dvA[0][2] += Wv0 * v02 + w0 * rh2;
        dvA[1][0] += Wv1 * v10 + w1 * rh0;
        dvA[1][1] += Wv1 * v11 + w1 * rh1;
        dvA[1][2] += Wv1 * v12 + w1 * rh2;
      }
    }

    // quad reduction
#pragma unroll
    for (int a = 0; a < 2; ++a) {
      dsA[a] += __shfl_xor(dsA[a], 16);
      dsA[a] += __shfl_xor(dsA[a], 32);
#pragma unroll
      for (int c = 0; c < 3; ++c) {
        dvA[a][c] += __shfl_xor(dvA[a][c], 16);
        dvA[a][c] += __shfl_xor(dvA[a][c], 32);
      }
    }

    // LDS-staged coalesced output: ob[0:128]=s row, ob[128:512]=v row
    __syncthreads();                 // all h_buf readers done
    float* ob = (float*)h_buf;       // 512 floats = 2048B <= 4352B
    if (q == 0) {
      ob[f0] = dsA[0];
      ob[f1] = dsA[1];
#pragma unroll
      for (int c = 0; c < 3; ++c) {
        ob[128 + f0 * 3 + c] = dvA[0][c];
        ob[128 + f1 * 3 + c] = dvA[1][c];
      }
    }
    __syncthreads();
    if (tid < 32)
      ((float4*)(out_s + (size_t)n * FF))[tid] = ((const float4*)ob)[tid];
    else if (tid < 128)
      ((float4*)(out_v + (size_t)n * C3F))[tid - 32] = ((const float4*)ob)[tid];
  }
}

// ==================== fallback: edge-parallel, inline phi, atomics (no ws) ============
__global__ __launch_bounds__(256, 2)
void edge_kernel(const float* __restrict__ sfeat, const float* __restrict__ v,
                 const float* __restrict__ e_ij, const float* __restrict__ r_hat,
                 const float* __restrict__ phi_W, const float* __restrict__ phi_b,
                 const float* __restrict__ f1_W, const float* __restrict__ f1_b,
                 const float* __restrict__ f2_W, const float* __restrict__ f2_b,
                 const int* __restrict__ edge_index,
                 float* __restrict__ out_s, float* __restrict__ out_v) {
  __shared__ float h_t[FF * HP];
  __shared__ float w_ch[KC * C3F];
  __shared__ float e_t[TE * RBFD];
  __shared__ float f1_lds[RBFD * FF];
  __shared__ int src_lds[TE], dst_lds[TE];
  __shared__ float rh_lds[TE * 3];
  __shared__ float s_t[FF * HP];

  const int tid = threadIdx.x;
  const int e0 = blockIdx.x * TE;

  if (tid < TE) {
    src_lds[tid] = edge_index[e0 + tid];
    dst_lds[tid] = edge_index[EE + e0 + tid];
  }
  if (tid < TE * 3) rh_lds[tid] = r_hat[(size_t)e0 * 3 + tid];
  for (int i = tid; i < TE * RBFD; i += 256) e_t[i] = e_ij[(size_t)e0 * RBFD + i];
  for (int i = tid; i < RBFD * FF; i += 256) f1_lds[i] = f1_W[i];
  __syncthreads();

  for (int i = tid; i < TE * FF; i += 256) {
    int e = i >> 7, f = i & 127;
    float x = f1_b[f];
#pragma unroll
    for (int k = 0; k < RBFD; ++k) x += e_t[e * RBFD + k] * f1_lds[k * FF + f];
    h_t[f * HP + e] = softplus_m_log2(x);
  }
  for (int i = tid; i < TE * (FF / 4); i += 256) {
    int e = i >> 5, k4 = i & 31;
    int d = dst_lds[e];
    float4 sv = *(const float4*)(sfeat + (size_t)d * FF + k4 * 4);
    s_t[(k4 * 4 + 0) * HP + e] = sv.x;
    s_t[(k4 * 4 + 1) * HP + e] = sv.y;
    s_t[(k4 * 4 + 2) * HP + e] = sv.z;
    s_t[(k4 * 4 + 3) * HP + e] = sv.w;
  }

  const int tc = tid & 31, tr = tid >> 5;
  float facc[3][4][4];
  float pacc[2][4][4];
#pragma unroll
  for (int g = 0; g < 3; ++g)
#pragma unroll
    for (int a = 0; a < 4; ++a)
#pragma unroll
      for (int b = 0; b < 4; ++b) facc[g][a][b] = 0.f;
#pragma unroll
  for (int g = 0; g < 2; ++g)
#pragma unroll
    for (int a = 0; a < 4; ++a)
#pragma unroll
      for (int b = 0; b < 4; ++b) pacc[g][a][b] = 0.f;

  for (int kc = 0; kc < FF / KC; ++kc) {
    __syncthreads();
    for (int i = tid; i < KC * C3F / 4; i += 256)
      *(float4*)&w_ch[i * 4] =
          *(const float4*)(f2_W + (size_t)kc * KC * C3F + i * 4);
    __syncthreads();
#pragma unroll
    for (int k = 0; k < KC; ++k) {
      float4 h4 = *(const float4*)&h_t[(kc * KC + k) * HP + tr * 4];
      float hr[4] = {h4.x, h4.y, h4.z, h4.w};
#pragma unroll
      for (int g = 0; g < 3; ++g) {
        float4 w4 = *(const float4*)&w_ch[k * C3F + g * 128 + tc * 4];
        float wr[4] = {w4.x, w4.y, w4.z, w4.w};
#pragma unroll
        for (int er = 0; er < 4; ++er)
#pragma unroll
          for (int fc = 0; fc < 4; ++fc) facc[g][er][fc] += hr[er] * wr[fc];
      }
    }
  }

  for (int kc = 0; kc < FF / KC; ++kc) {
    __syncthreads();
    for (int i = tid; i < KC * 64; i += 256) {
      int k = i >> 6, j4 = i & 63;
      int j = j4 * 4;
      int col = (j < 128) ? j : (j + 128);
      *(float4*)&w_ch[k * C3F + j] =
          *(const float4*)(phi_W + (size_t)(kc * KC + k) * C3F + col);
    }
    __syncthreads();
#pragma unroll
    for (int k = 0; k < KC; ++k) {
      float4 s4 = *(const float4*)&s_t[(kc * KC + k) * HP + tr * 4];
      float sr[4] = {s4.x, s4.y, s4.z, s4.w};
#pragma unroll
      for (int g = 0; g < 2; ++g) {
        float4 w4 = *(const float4*)&w_ch[k * C3F + g * 128 + tc * 4];
        float wr[4] = {w4.x, w4.y, w4.z, w4.w};
#pragma unroll
        for (int er = 0; er < 4; ++er)
#pragma unroll
          for (int fc = 0; fc < 4; ++fc) pacc[g][er][fc] += sr[er] * wr[fc];
      }
    }
  }

  const int f0 = tc * 4;
  float4 bs4 = *(const float4*)(f2_b + f0);
  float4 bv4 = *(const float4*)(f2_b + FF + f0);
  float4 br4 = *(const float4*)(f2_b + 2 * FF + f0);
  float bs[4] = {bs4.x, bs4.y, bs4.z, bs4.w};
  float bv[4] = {bv4.x, bv4.y, bv4.z, bv4.w};
  float br[4] = {br4.x, br4.y, br4.z, br4.w};
  float4 p0b = *(const float4*)(phi_b + f0);
  float4 p2b = *(const float4*)(phi_b + 256 + f0);
  float pb0[4] = {p0b.x, p0b.y, p0b.z, p0b.w};
  float pb2[4] = {p2b.x, p2b.y, p2b.z, p2b.w};

#pragma unroll
  for (int er = 0; er < 4; ++er) {
    const int e = tr * 4 + er;
    const int sg = src_lds[e];
    const int dg = dst_lds[e];
    const float r0c = rh_lds[e * 3 + 0];
    const float r1c = rh_lds[e * 3 + 1];
    const float r2c = rh_lds[e * 3 + 2];

    float ps[4], pr[4];
#pragma unroll
    for (int fc = 0; fc < 4; ++fc) {
      ps[fc] = pacc[0][er][fc] + pb0[fc];
      pr[fc] = pacc[1][er][fc] + pb2[fc];
    }

    float pv[12];
    const float* vp = v + ((size_t)dg * FF + f0) * 3;
    float4 v0 = *(const float4*)(vp);
    float4 v1 = *(const float4*)(vp + 4);
    float4 v2 = *(const float4*)(vp + 8);
    pv[0] = v0.x; pv[1] = v0.y; pv[2] = v0.z; pv[3] = v0.w;
    pv[4] = v1.x; pv[5] = v1.y; pv[6] = v1.z; pv[7] = v1.w;
    pv[8] = v2.x; pv[9] = v2.y; pv[10] = v2.z; pv[11] = v2.w;

    float* os = out_s + (size_t)sg * FF + f0;
    float* ov = out_v + ((size_t)sg * FF + f0) * 3;
#pragma unroll
    for (int fc = 0; fc < 4; ++fc) {
      float Ws = facc[0][er][fc] + bs[fc];
      float Wv = facc[1][er][fc] + bv[fc];
      float Wr = facc[2][er][fc] + br[fc];
      atomicAdd(os + fc, Ws * ps[fc]);
      float wrp = Wr * pr[fc];
      atomicAdd(ov + fc * 3 + 0, Wv * pv[fc * 3 + 0] + wrp * r0c);
      atomicAdd(ov + fc * 3 + 1, Wv * pv[fc * 3 + 1] + wrp * r1c);
      atomicAdd(ov + fc * 3 + 2, Wv * pv[fc * 3 + 2] + wrp * r2c);
    }
  }
}

extern "C" void kernel_launch(void* const* d_in, const int* in_sizes, int n_in,
                              void* d_out, int out_size, void* d_ws, size_t ws_size,
                              hipStream_t stream) {
  const float* s      = (const float*)d_in[0];
  const float* v      = (const float*)d_in[1];
  const float* e_ij   = (const float*)d_in[2];
  const float* r_hat  = (const float*)d_in[3];
  const float* phi_W  = (const float*)d_in[4];
  const float* phi_b  = (const float*)d_in[5];
  const float* f1_W   = (const float*)d_in[6];
  const float* f1_b   = (const float*)d_in[7];
  const float* f2_W   = (const float*)d_in[8];
  const float* f2_b   = (const float*)d_in[9];
  const int* edge_index = (const int*)d_in[10];

  float* out = (float*)d_out;
  float* out_s = out;                       // (N, F)
  float* out_v = out + (size_t)NN * FF;     // (N, F, 3)

  // ws layout: row_start[50008] | cursor[NN] | perm[EE] | phi_b16[NN*256] bf16
  //            | f2t[384*128] bf16 | f1t[128*40] bf16 | v_b16[NN*384] bf16 (optional)
  int* row_start = (int*)d_ws;
  int* cursor    = row_start + 50008;
  int* perm      = cursor + NN;
  short* phi_b16 = (short*)(perm + EE);
  short* f2t     = phi_b16 + (size_t)NN * 256;
  short* f1t     = f2t + C3F * FF;
  short* v_b16   = f1t + FF * 40;
  const size_t mid_bytes  = (size_t)(50008 + NN + EE) * 4 +
                            ((size_t)NN * 256 + C3F * FF + FF * 40) * 2;
  const size_t full_bytes = mid_bytes + (size_t)NN * 384 * 2;

  if (ws_size >= mid_bytes) {
    hipMemsetAsync(cursor, 0, (size_t)NN * sizeof(int), stream);
    hist_kernel<<<(EE + 255) / 256, 256, 0, stream>>>(edge_index, cursor);
    scan_kernel<<<1, 1024, 0, stream>>>(cursor, row_start);
    fill_kernel<<<(EE + 255) / 256, 256, 0, stream>>>(edge_index, cursor, perm);
    conv_kernel<<<(C3F * FF + 255) / 256, 256, 0, stream>>>(f1_W, f2_W, f1t, f2t);
    phi_kernel<<<(NN + TE - 1) / TE, 256, 0, stream>>>(s, phi_W, phi_b, phi_b16);
    if (ws_size >= full_bytes) {
      vconv_kernel<<<(NN * 384 + 255) / 256, 256, 0, stream>>>(v, v_b16);
      node_mfma_kernel<true><<<768, 256, 0, stream>>>(
          v, v_b16, e_ij, r_hat, f1_b, f2_b, edge_index, row_start, perm,
          phi_b16, f1t, f2t, out_s, out_v);
    } else {
      node_mfma_kernel<false><<<768, 256, 0, stream>>>(
          v, nullptr, e_ij, r_hat, f1_b, f2_b, edge_index, row_start, perm,
          phi_b16, f1t, f2t, out_s, out_v);
    }
  } else {
    hipMemsetAsync(d_out, 0, (size_t)out_size * sizeof(float), stream);
    edge_kernel<<<EE / TE, 256, 0, stream>>>(
        s, v, e_ij, r_hat, phi_W, phi_b, f1_W, f1_b, f2_W, f2_b, edge_index,
        out_s, out_v);
  }
}